// Round 20
// baseline (63.486 us; speedup 1.0000x reference)
//
#include <hip/hip_runtime.h>
#include <hip/hip_bf16.h>

// 3D db4 DWT, fused single kernel.
// Round-20 = Round-19 with the preprocessor bug fixed: `D_##1.y` pasted P with
// pp-number token `1.y` -> invalid token P1.y. Fix: (D_##1).y everywhere.
// Design unchanged: ablate global_load_lds entirely. Each lane loads its own
// 10-float tap window (5 x dwordx2, 8B-aligned, base gb=2*(wo0+wo)-4 clamped
// to [0,246]) straight to registers; edge lanes use register tap fixups.
// No Ring / ds_read / vmcnt asm. Register double-buffer P/Q, explicit 28-step
// unroll. LDS = Vbuf only (32KB) -> 4 blocks/CU. H/T phases = r11 verbatim.
// x: [4,3,32,256,256] f32 -> out: [4,24,16,128,128] f32

#define CC 3
#define TT 32
#define HH 256
#define WW 256
#define TOH 16
#define HOH 128
#define WOH 128
#define TH 4
#define TW 32
#define NTHREADS 512
#define VSTR 512

constexpr float GLO[8] = {
     0.23037781330885523f,  0.7148465705525415f,   0.6308807679295904f,
    -0.02798376941698385f, -0.18703481171888114f,  0.030841381835986965f,
     0.032883011666982945f, -0.010597401784997278f };
constexpr float GHI[8] = {
    -0.010597401784997278f, -0.032883011666982945f, 0.030841381835986965f,
     0.18703481171888114f,  -0.02798376941698385f,  -0.6308807679295904f,
     0.7148465705525415f,   -0.23037781330885523f };

__device__ __forceinline__ int refl(int p, int n) {
    p = p < 0 ? -p : p;
    p = p >= n ? 2 * n - 2 - p : p;
    return p;
}

__global__ __launch_bounds__(NTHREADS)
void dwt3d_db4_kernel(const float* __restrict__ x, float* __restrict__ out) {
    __shared__ __hip_bfloat16 Vbuf[TT * VSTR];    // 32768 B (only LDS)

    const int tid  = threadIdx.x;
    const int wid  = tid >> 6;
    const int lane = tid & 63;
    const int wo   = lane & 31;
    const int p    = lane >> 5;          // row parity (0=even,1=odd)

    // XCD-aware bijective swizzle: 1536 blocks, 8 XCDs, 192 per chunk.
    const int lin = blockIdx.x;
    const int nid = (lin & 7) * 192 + (lin >> 3);
    const int wo0 = (nid & 3) * TW;
    const int ho0 = ((nid >> 2) & 31) * TH;
    const int bz  = nid >> 7;            // b*CC + c
    const int b = bz / CC, c = bz - b * CC;

    const float* xs = x + (size_t)bz * (TT * HH * WW);
    const int t0 = wid * 4;

    // per-lane tap-window base (even -> 8B-aligned), clamped in-range
    int gb = 2 * (wo0 + wo) - 4;
    gb = gb < 0 ? 0 : (gb > 246 ? 246 : gb);
    const int goff = gb >> 1;            // float2 index within a row

    // parity-selected H weights (r11)
    float wH0[4], wH1[4];
#pragma unroll
    for (int d = 0; d < 4; ++d) {
        wH0[d] = p ? GLO[2 * d + 1] : GLO[2 * d];
        wH1[d] = p ? GHI[2 * d + 1] : GHI[2 * d];
    }
    const int vcolbase = p * 128 + wo;

    float vacc0[2][4], vacc1[2][4];
#pragma unroll
    for (int sh = 0; sh < 2; ++sh)
#pragma unroll
        for (int ho = 0; ho < 4; ++ho) { vacc0[sh][ho] = 0.f; vacc1[sh][ho] = 0.f; }

    float2 P0, P1, P2, P3, P4, Q0, Q1, Q2, Q3, Q4;

// row pointer for iteration k (k is a literal): lane's parity row of pair k
#define ROWF2(k_) ((const float2*)(xs                                         \
        + (size_t)(t0 + (k_) / 7) * (HH * WW)                                 \
        + (size_t)refl(2 * ho0 - 3 + 2 * ((k_) % 7) + p, HH) * WW) + goff)

#define LOADD(D_, k_) do { const float2* rp_ = ROWF2(k_);                     \
        (D_##0) = rp_[0]; (D_##1) = rp_[1]; (D_##2) = rp_[2];                 \
        (D_##3) = rp_[3]; (D_##4) = rp_[4]; } while (0)

#define COMPUTE(D_, k_) do {                                                  \
    float a0 = (D_##0).y, a1 = (D_##1).x, a2 = (D_##1).y, a3 = (D_##2).x,     \
          a4 = (D_##2).y, a5 = (D_##3).x, a6 = (D_##3).y, a7 = (D_##4).x;     \
    if (wo0 == 0) {                                                           \
        if (wo == 0) { a0 = (D_##1).y; a1 = (D_##1).x; a2 = (D_##0).y;        \
                       a3 = (D_##0).x; a4 = (D_##0).y; a5 = (D_##1).x;        \
                       a6 = (D_##1).y; a7 = (D_##2).x; }                      \
        else if (wo == 1) { a0 = (D_##0).y; a1 = (D_##0).x; a2 = (D_##0).y;   \
                            a3 = (D_##1).x; a4 = (D_##1).y; a5 = (D_##2).x;   \
                            a6 = (D_##2).y; a7 = (D_##3).x; }                 \
    } else if (wo0 == 96) {                                                   \
        if (wo == 30) { a0 = (D_##1).y; a1 = (D_##2).x; a2 = (D_##2).y;       \
                        a3 = (D_##3).x; a4 = (D_##3).y; a5 = (D_##4).x;       \
                        a6 = (D_##4).y; a7 = (D_##4).x; }                     \
        else if (wo == 31) { a0 = (D_##2).y; a1 = (D_##3).x; a2 = (D_##3).y;  \
                             a3 = (D_##4).x; a4 = (D_##4).y; a5 = (D_##4).x;  \
                             a6 = (D_##3).y; a7 = (D_##3).x; }                \
    }                                                                         \
    float m_lo, m_hi;                                                         \
    m_lo = a0 * GLO[0]; m_hi = a0 * GHI[0];                                   \
    m_lo = fmaf(a1, GLO[1], m_lo); m_hi = fmaf(a1, GHI[1], m_hi);             \
    m_lo = fmaf(a2, GLO[2], m_lo); m_hi = fmaf(a2, GHI[2], m_hi);             \
    m_lo = fmaf(a3, GLO[3], m_lo); m_hi = fmaf(a3, GHI[3], m_hi);             \
    m_lo = fmaf(a4, GLO[4], m_lo); m_hi = fmaf(a4, GHI[4], m_hi);             \
    m_lo = fmaf(a5, GLO[5], m_lo); m_hi = fmaf(a5, GHI[5], m_hi);             \
    m_lo = fmaf(a6, GLO[6], m_lo); m_hi = fmaf(a6, GHI[6], m_hi);             \
    m_lo = fmaf(a7, GLO[7], m_lo); m_hi = fmaf(a7, GHI[7], m_hi);             \
    const int kk = (k_) % 7;                                                  \
    _Pragma("unroll")                                                         \
    for (int ho = 0; ho < 4; ++ho) {                                          \
        const int d = kk - ho;                                                \
        if (d >= 0 && d < 4) {                                                \
            vacc0[0][ho] = fmaf(m_lo, wH0[d], vacc0[0][ho]);                  \
            vacc0[1][ho] = fmaf(m_lo, wH1[d], vacc0[1][ho]);                  \
            vacc1[0][ho] = fmaf(m_hi, wH0[d], vacc1[0][ho]);                  \
            vacc1[1][ho] = fmaf(m_hi, wH1[d], vacc1[1][ho]);                  \
        }                                                                     \
    }                                                                         \
    if (kk == 6) {                                                            \
        const int t = t0 + (k_) / 7;                                          \
        _Pragma("unroll")                                                     \
        for (int sh = 0; sh < 2; ++sh)                                        \
            _Pragma("unroll")                                                 \
            for (int ho = 0; ho < 4; ++ho) {                                  \
                const float send = p ? vacc0[sh][ho] : vacc1[sh][ho];         \
                const float keep = p ? vacc1[sh][ho] : vacc0[sh][ho];         \
                const float recv = __shfl_xor(send, 32, 64);                  \
                Vbuf[t * VSTR + sh * 256 + vcolbase + ho * 32] =              \
                    __float2bfloat16(keep + recv);                            \
                vacc0[sh][ho] = 0.f; vacc1[sh][ho] = 0.f;                     \
            }                                                                 \
    }                                                                         \
} while (0)

#define STEP(CUR_, NXT_, k_) do {                                             \
        LOADD(NXT_, (k_) + 1); COMPUTE(CUR_, k_); } while (0)

    LOADD(P, 0);
    STEP(P, Q, 0);  STEP(Q, P, 1);  STEP(P, Q, 2);  STEP(Q, P, 3);
    STEP(P, Q, 4);  STEP(Q, P, 5);  STEP(P, Q, 6);  STEP(Q, P, 7);
    STEP(P, Q, 8);  STEP(Q, P, 9);  STEP(P, Q, 10); STEP(Q, P, 11);
    STEP(P, Q, 12); STEP(Q, P, 13); STEP(P, Q, 14); STEP(Q, P, 15);
    STEP(P, Q, 16); STEP(Q, P, 17); STEP(P, Q, 18); STEP(Q, P, 19);
    STEP(P, Q, 20); STEP(Q, P, 21); STEP(P, Q, 22); STEP(Q, P, 23);
    STEP(P, Q, 24); STEP(Q, P, 25); STEP(P, Q, 26);
    COMPUTE(Q, 27);

    __syncthreads();

    // ---- T transform (registers) + store (r11 verbatim) ----
    float v[TT];
#pragma unroll
    for (int t = 0; t < TT; ++t) v[t] = __bfloat162float(Vbuf[t * VSTR + tid]);

    const int subhw = tid >> 7;
    const int hoq   = (tid >> 5) & 3;
    const int wo2   = tid & 31;

    const size_t hw = (size_t)(ho0 + hoq) * WOH + (wo0 + wo2);
    const size_t ch_lo = (size_t)(subhw * CC + c);
    const size_t ch_hi = (size_t)((4 + subhw) * CC + c);
    const size_t o_lo = (((size_t)b * 24 + ch_lo) * TOH) * (HOH * WOH) + hw;
    const size_t o_hi = (((size_t)b * 24 + ch_hi) * TOH) * (HOH * WOH) + hw;

#pragma unroll
    for (int to = 0; to < TOH; ++to) {
        float lo = 0.f, hi = 0.f;
#pragma unroll
        for (int j = 0; j < 8; ++j) {
            int q = 2 * to + j - 3;
            q = q < 0 ? -q : q;
            q = q >= TT ? 2 * TT - 2 - q : q;   // folds to constant
            lo = fmaf(v[q], GLO[j], lo);
            hi = fmaf(v[q], GHI[j], hi);
        }
        out[o_lo + (size_t)to * (HOH * WOH)] = lo;
        out[o_hi + (size_t)to * (HOH * WOH)] = hi;
    }
}

extern "C" void kernel_launch(void* const* d_in, const int* in_sizes, int n_in,
                              void* d_out, int out_size, void* d_ws, size_t ws_size,
                              hipStream_t stream) {
    (void)in_sizes; (void)n_in; (void)d_ws; (void)ws_size; (void)out_size;
    const float* x = (const float*)d_in[0];
    float* out = (float*)d_out;
    dim3 grid(1536, 1, 1);
    dim3 block(NTHREADS);
    hipLaunchKernelGGL(dwt3d_db4_kernel, grid, block, 0, stream, x, out);
}

// Round 21
// 46.030 us; speedup vs baseline: 1.3792x; 1.3792x over previous
//
#include <hip/hip_runtime.h>
#include <hip/hip_bf16.h>

// 3D db4 DWT, fused single kernel.
// Round-21: r11 structure with DEEP DMA pipeline — NSLOTS 8->16, DEPTH 6->14
// rows in flight (28 insts, cover = 6 iteration bodies ~900cy >= HBM latency).
// Gates: vmcnt(24) steady; tail 20/16/12/8/4/0 at k=22..27. No same-slot
// reuse (1 slot slack). Ring 36.9KB + Vbuf 32KB = 69.6KB -> 2 blocks/CU.
// Tests the last unvaried structural parameter: gate-lookahead depth.
// x: [4,3,32,256,256] f32 -> out: [4,24,16,128,128] f32

#define CC 3
#define TT 32
#define HH 256
#define WW 256
#define TOH 16
#define HOH 128
#define WOH 128
#define TH 4
#define TW 32
#define NROWS 14
#define RSLOT 72        // ring slot stride (floats)
#define RSLOT2 36
#define NSLOTS 16
#define DEPTH 14        // rows in flight
#define NTHREADS 512
#define VSTR 512
#define NRR (4*NROWS)   // 56 rows per wave

constexpr float GLO[8] = {
     0.23037781330885523f,  0.7148465705525415f,   0.6308807679295904f,
    -0.02798376941698385f, -0.18703481171888114f,  0.030841381835986965f,
     0.032883011666982945f, -0.010597401784997278f };
constexpr float GHI[8] = {
    -0.010597401784997278f, -0.032883011666982945f, 0.030841381835986965f,
     0.18703481171888114f,  -0.02798376941698385f,  -0.6308807679295904f,
     0.7148465705525415f,   -0.23037781330885523f };

__device__ __forceinline__ int refl(int p, int n) {
    p = p < 0 ? -p : p;
    p = p >= n ? 2 * n - 2 - p : p;
    return p;
}

__global__ __launch_bounds__(NTHREADS)
void dwt3d_db4_kernel(const float* __restrict__ x, float* __restrict__ out) {
    __shared__ float Ring[8 * NSLOTS * RSLOT];    // 36864 B
    __shared__ __hip_bfloat16 Vbuf[TT * VSTR];    // 32768 B

    const int tid  = threadIdx.x;
    const int wid  = tid >> 6;
    const int lane = tid & 63;
    const int wo   = lane & 31;
    const int p    = lane >> 5;          // row parity (0=even,1=odd)

    // XCD-aware bijective swizzle: 1536 blocks, 8 XCDs, 192 per chunk.
    const int lin = blockIdx.x;
    const int nid = (lin & 7) * 192 + (lin >> 3);
    const int wo0 = (nid & 3) * TW;
    const int ho0 = ((nid >> 2) & 31) * TH;
    const int bz  = nid >> 7;            // b*CC + c
    const int b = bz / CC, c = bz - b * CC;

    const float* xs = x + (size_t)bz * (TT * HH * WW);
    const int t0 = wid * 4;

    // r11 overlap staging: chunk-0 cols -3..60 -> floats 0..63 (dest lp_);
    // chunk-1 cols 3..66 -> floats 6..69 (dest lp_+6). Overlap floats 6..63
    // written with IDENTICAL values by both chunks -> benign race, no spill.
    const int gcol0 = refl(2 * wo0 - 3 + lane, WW);
    const int gcol1 = refl(2 * wo0 + 3 + lane, WW);

    // parity-selected H weights
    float wH0[4], wH1[4];
#pragma unroll
    for (int d = 0; d < 4; ++d) {
        wH0[d] = p ? GLO[2 * d + 1] : GLO[2 * d];
        wH1[d] = p ? GHI[2 * d + 1] : GHI[2 * d];
    }

    const int ringbase = wid * (NSLOTS * RSLOT);
    const float2* Ring2 = (const float2*)Ring;
    const int r2base = wid * (NSLOTS * RSLOT2) + p * RSLOT2 + wo;
    const int vcolbase = p * 128 + wo;

#define ISSUE(rr_) do {                                                       \
        const int t_ = (rr_) / NROWS, r_ = (rr_) % NROWS;                     \
        const int gr_ = refl(2 * ho0 - 3 + r_, HH);                           \
        const float* rowp_ = xs + (size_t)(t0 + t_) * (HH * WW) + gr_ * WW;   \
        float* lp_ = &Ring[ringbase + ((rr_) & (NSLOTS - 1)) * RSLOT];        \
        __builtin_amdgcn_global_load_lds(                                     \
            (const __attribute__((address_space(1))) void*)(rowp_ + gcol0),   \
            (__attribute__((address_space(3))) void*)lp_, 4, 0, 0);           \
        __builtin_amdgcn_global_load_lds(                                     \
            (const __attribute__((address_space(1))) void*)(rowp_ + gcol1),   \
            (__attribute__((address_space(3))) void*)(lp_ + 6), 4, 0, 0);     \
    } while (0)

    float vacc0[2][4], vacc1[2][4];
#pragma unroll
    for (int sh = 0; sh < 2; ++sh)
#pragma unroll
        for (int ho = 0; ho < 4; ++ho) { vacc0[sh][ho] = 0.f; vacc1[sh][ho] = 0.f; }

    // prologue: DEPTH=14 rows in flight (28 insts)
#pragma unroll
    for (int rr = 0; rr < DEPTH; ++rr) ISSUE(rr);

#pragma unroll
    for (int k = 0; k < 28; ++k) {
        // Gate on rows 2k,2k+1. Issued through row 2k+13 (k<=21) -> allow
        // rows 2k+2..2k+13 = 24 insts outstanding. Tail tightens by 4/iter.
        if (k <= 21)      asm volatile("s_waitcnt vmcnt(24)" ::: "memory");
        else if (k == 22) asm volatile("s_waitcnt vmcnt(20)" ::: "memory");
        else if (k == 23) asm volatile("s_waitcnt vmcnt(16)" ::: "memory");
        else if (k == 24) asm volatile("s_waitcnt vmcnt(12)" ::: "memory");
        else if (k == 25) asm volatile("s_waitcnt vmcnt(8)"  ::: "memory");
        else if (k == 26) asm volatile("s_waitcnt vmcnt(4)"  ::: "memory");
        else              asm volatile("s_waitcnt vmcnt(0)"  ::: "memory");

        // lane's row = 2k+p; 8 taps as 4 float2 (slot index compile-time)
        const int soff = ((2 * k) & (NSLOTS - 1)) * RSLOT2;
        const float2 d0 = Ring2[r2base + soff + 0];
        const float2 d1 = Ring2[r2base + soff + 1];
        const float2 d2 = Ring2[r2base + soff + 2];
        const float2 d3 = Ring2[r2base + soff + 3];

        float a0 = d0.x, a1 = d0.y, a2 = d1.x, a3 = d1.y;
        float a4 = d2.x, a5 = d2.y, a6 = d3.x, a7 = d3.y;

        float m_lo, m_hi;
        m_lo = a0 * GLO[0]; m_hi = a0 * GHI[0];
        m_lo = fmaf(a1, GLO[1], m_lo); m_hi = fmaf(a1, GHI[1], m_hi);
        m_lo = fmaf(a2, GLO[2], m_lo); m_hi = fmaf(a2, GHI[2], m_hi);
        m_lo = fmaf(a3, GLO[3], m_lo); m_hi = fmaf(a3, GHI[3], m_hi);
        m_lo = fmaf(a4, GLO[4], m_lo); m_hi = fmaf(a4, GHI[4], m_hi);
        m_lo = fmaf(a5, GLO[5], m_lo); m_hi = fmaf(a5, GHI[5], m_hi);
        m_lo = fmaf(a6, GLO[6], m_lo); m_hi = fmaf(a6, GHI[6], m_hi);
        m_lo = fmaf(a7, GLO[7], m_lo); m_hi = fmaf(a7, GHI[7], m_hi);

        // refill: rows 2k+14, 2k+15 (slots 1 clear of any unread row)
        if (2 * k + DEPTH < NRR) { ISSUE(2 * k + DEPTH); ISSUE(2 * k + DEPTH + 1); }

        // H accumulation (parity-local)
        const int kk = k % 7;
#pragma unroll
        for (int ho = 0; ho < 4; ++ho) {
            const int d = kk - ho;
            if (d >= 0 && d < 4) {
                vacc0[0][ho] = fmaf(m_lo, wH0[d], vacc0[0][ho]);
                vacc0[1][ho] = fmaf(m_lo, wH1[d], vacc0[1][ho]);
                vacc1[0][ho] = fmaf(m_hi, wH0[d], vacc1[0][ho]);
                vacc1[1][ho] = fmaf(m_hi, wH1[d], vacc1[1][ho]);
            }
        }

        // slice boundary: merge parity partials across lane pairs -> Vbuf
        if (kk == 6) {
            const int t = t0 + k / 7;
#pragma unroll
            for (int sh = 0; sh < 2; ++sh)
#pragma unroll
                for (int ho = 0; ho < 4; ++ho) {
                    const float send = p ? vacc0[sh][ho] : vacc1[sh][ho];
                    const float keep = p ? vacc1[sh][ho] : vacc0[sh][ho];
                    const float recv = __shfl_xor(send, 32, 64);
                    Vbuf[t * VSTR + sh * 256 + vcolbase + ho * 32] =
                        __float2bfloat16(keep + recv);
                    vacc0[sh][ho] = 0.f; vacc1[sh][ho] = 0.f;
                }
        }
    }

    __syncthreads();

    // ---- T transform (registers) + store (r11 verbatim) ----
    float v[TT];
#pragma unroll
    for (int t = 0; t < TT; ++t) v[t] = __bfloat162float(Vbuf[t * VSTR + tid]);

    const int subhw = tid >> 7;
    const int hoq   = (tid >> 5) & 3;
    const int wo2   = tid & 31;

    const size_t hw = (size_t)(ho0 + hoq) * WOH + (wo0 + wo2);
    const size_t ch_lo = (size_t)(subhw * CC + c);
    const size_t ch_hi = (size_t)((4 + subhw) * CC + c);
    const size_t o_lo = (((size_t)b * 24 + ch_lo) * TOH) * (HOH * WOH) + hw;
    const size_t o_hi = (((size_t)b * 24 + ch_hi) * TOH) * (HOH * WOH) + hw;

#pragma unroll
    for (int to = 0; to < TOH; ++to) {
        float lo = 0.f, hi = 0.f;
#pragma unroll
        for (int j = 0; j < 8; ++j) {
            int q = 2 * to + j - 3;
            q = q < 0 ? -q : q;
            q = q >= TT ? 2 * TT - 2 - q : q;   // folds to constant
            lo = fmaf(v[q], GLO[j], lo);
            hi = fmaf(v[q], GHI[j], hi);
        }
        out[o_lo + (size_t)to * (HOH * WOH)] = lo;
        out[o_hi + (size_t)to * (HOH * WOH)] = hi;
    }
}

extern "C" void kernel_launch(void* const* d_in, const int* in_sizes, int n_in,
                              void* d_out, int out_size, void* d_ws, size_t ws_size,
                              hipStream_t stream) {
    (void)in_sizes; (void)n_in; (void)d_ws; (void)ws_size; (void)out_size;
    const float* x = (const float*)d_in[0];
    float* out = (float*)d_out;
    dim3 grid(1536, 1, 1);
    dim3 block(NTHREADS);
    hipLaunchKernelGGL(dwt3d_db4_kernel, grid, block, 0, stream, x, out);
}